// Round 1
// baseline (2788.964 us; speedup 1.0000x reference)
//
#include <hip/hip_runtime.h>

#define N_NODES 100000
#define N_EDGES 1600000
#define C_IN 128
#define C_H 64
#define C_OUT 40

// ---------------------------------------------------------------------------
// K1: y1 = x @ Wl1^T   [N, 64]
// wave-per-row; Wl1 transposed into LDS [k][c]; x rows staged 4-at-a-time.
// ---------------------------------------------------------------------------
__global__ __launch_bounds__(256) void k_gemm_y1(const float* __restrict__ x,
                                                 const float* __restrict__ Wl1,
                                                 float* __restrict__ y1) {
    __shared__ float Wt[C_IN * C_H];   // 32 KB, Wt[k*64+c] = Wl1[c*128+k]
    __shared__ float xs[4][C_IN];      // 2 KB
    for (int i = threadIdx.x; i < C_IN * C_H; i += 256) {
        int k = i >> 6, c = i & 63;
        Wt[i] = Wl1[c * C_IN + k];
    }
    __syncthreads();
    const int wave = threadIdx.x >> 6, lane = threadIdx.x & 63;
    for (int r0 = blockIdx.x * 4; r0 < N_NODES; r0 += gridDim.x * 4) {
        for (int i = threadIdx.x; i < 4 * C_IN; i += 256) {
            int rr = r0 + (i >> 7);
            xs[i >> 7][i & 127] = (rr < N_NODES) ? x[(long)rr * C_IN + (i & 127)] : 0.f;
        }
        __syncthreads();
        int r = r0 + wave;
        if (r < N_NODES) {
            float acc = 0.f;
#pragma unroll 8
            for (int k = 0; k < C_IN; ++k)
                acc = fmaf(xs[wave][k], Wt[k * C_H + lane], acc);
            y1[(long)r * C_H + lane] = acc;
        }
        __syncthreads();
    }
}

// ---------------------------------------------------------------------------
// K2: agg1[dst] += y1[src]  (64 ch, float4 per thread, 16 threads/edge)
//     cnt[dst] += 1 (lane g==0)
// ---------------------------------------------------------------------------
__global__ __launch_bounds__(256) void k_agg1(const int* __restrict__ ei,
                                              const float* __restrict__ y1,
                                              float* __restrict__ agg1,
                                              float* __restrict__ cnt) {
    long tid = (long)blockIdx.x * 256 + threadIdx.x;
    int e = (int)(tid >> 4), g = (int)(tid & 15);
    int src = ei[e], dst = ei[N_EDGES + e];
    const float4 v = *(const float4*)(y1 + ((long)src << 6) + (g << 2));
    float* p = agg1 + ((long)dst << 6) + (g << 2);
    atomicAdd(p + 0, v.x);
    atomicAdd(p + 1, v.y);
    atomicAdd(p + 2, v.z);
    atomicAdd(p + 3, v.w);
    if (g == 0) atomicAdd(cnt + dst, 1.0f);
}

// ---------------------------------------------------------------------------
// K3: fused  z1 = x@Wr1^T ;  h = relu(agg1/max(cnt,1) + bl1 + z1)  (LDS only)
//            y2 = h@Wl2^T ;  z2 = h@Wr2^T
// ---------------------------------------------------------------------------
__global__ __launch_bounds__(256) void k_layer1_finish(
    const float* __restrict__ x, const float* __restrict__ Wr1,
    const float* __restrict__ bl1, const float* __restrict__ Wl2,
    const float* __restrict__ Wr2, const float* __restrict__ agg1,
    const float* __restrict__ cnt, float* __restrict__ y2,
    float* __restrict__ z2) {
    __shared__ float Wr1t[C_IN * C_H];       // 32 KB  [k][c]
    __shared__ float W2t[2][C_H * C_OUT];    // 20.5 KB [k][cc]
    __shared__ float xs[4][C_IN];            // 2 KB
    __shared__ float hs[4][C_H];             // 1 KB
    for (int i = threadIdx.x; i < C_IN * C_H; i += 256) {
        int k = i >> 6, c = i & 63;
        Wr1t[i] = Wr1[c * C_IN + k];
    }
    for (int i = threadIdx.x; i < C_H * C_OUT; i += 256) {
        int k = i / C_OUT, cc = i - k * C_OUT;
        W2t[0][i] = Wl2[cc * C_H + k];
        W2t[1][i] = Wr2[cc * C_H + k];
    }
    __syncthreads();
    const int wave = threadIdx.x >> 6, lane = threadIdx.x & 63;
    for (int r0 = blockIdx.x * 4; r0 < N_NODES; r0 += gridDim.x * 4) {
        for (int i = threadIdx.x; i < 4 * C_IN; i += 256) {
            int rr = r0 + (i >> 7);
            xs[i >> 7][i & 127] = (rr < N_NODES) ? x[(long)rr * C_IN + (i & 127)] : 0.f;
        }
        __syncthreads();
        int r = r0 + wave;
        if (r < N_NODES) {
            float z = 0.f;
#pragma unroll 8
            for (int k = 0; k < C_IN; ++k)
                z = fmaf(xs[wave][k], Wr1t[k * C_H + lane], z);
            float inv = 1.f / fmaxf(cnt[r], 1.f);
            float h = fmaf(agg1[(long)r * C_H + lane], inv, bl1[lane] + z);
            hs[wave][lane] = fmaxf(h, 0.f);
        }
        __syncthreads();
        if (r < N_NODES && lane < C_OUT) {
            float a = 0.f, b = 0.f;
#pragma unroll 8
            for (int k = 0; k < C_H; ++k) {
                float hk = hs[wave][k];
                a = fmaf(hk, W2t[0][k * C_OUT + lane], a);
                b = fmaf(hk, W2t[1][k * C_OUT + lane], b);
            }
            y2[(long)r * C_OUT + lane] = a;
            z2[(long)r * C_OUT + lane] = b;
        }
        __syncthreads();
    }
}

// ---------------------------------------------------------------------------
// K4: agg2[dst] += y2[src]  (40 ch, float4 per thread, 10 threads/edge)
// ---------------------------------------------------------------------------
__global__ __launch_bounds__(256) void k_agg2(const int* __restrict__ ei,
                                              const float* __restrict__ y2,
                                              float* __restrict__ agg2) {
    long tid = (long)blockIdx.x * 256 + threadIdx.x;
    int e = (int)(tid / 10), g = (int)(tid - (long)e * 10);
    int src = ei[e], dst = ei[N_EDGES + e];
    const float4 v = *(const float4*)(y2 + (long)src * C_OUT + (g << 2));
    float* p = agg2 + (long)dst * C_OUT + (g << 2);
    atomicAdd(p + 0, v.x);
    atomicAdd(p + 1, v.y);
    atomicAdd(p + 2, v.z);
    atomicAdd(p + 3, v.w);
}

// ---------------------------------------------------------------------------
// K5: o = agg2/max(cnt,1) + bl2 + z2 ; softmax over 40 -> out. Wave per row.
// ---------------------------------------------------------------------------
__global__ __launch_bounds__(256) void k_out(const float* __restrict__ agg2,
                                             const float* __restrict__ z2,
                                             const float* __restrict__ cnt,
                                             const float* __restrict__ bl2,
                                             float* __restrict__ out) {
    const int wave = threadIdx.x >> 6, lane = threadIdx.x & 63;
    int r = blockIdx.x * 4 + wave;
    if (r >= N_NODES) return;
    float v = -__builtin_inff();
    if (lane < C_OUT) {
        float inv = 1.f / fmaxf(cnt[r], 1.f);
        v = fmaf(agg2[(long)r * C_OUT + lane], inv,
                 bl2[lane] + z2[(long)r * C_OUT + lane]);
    }
    float m = v;
    for (int s = 32; s; s >>= 1) m = fmaxf(m, __shfl_xor(m, s));
    float ex = (lane < C_OUT) ? __expf(v - m) : 0.f;
    float sum = ex;
    for (int s = 32; s; s >>= 1) sum += __shfl_xor(sum, s);
    if (lane < C_OUT) out[(long)r * C_OUT + lane] = ex / sum;
}

// ---------------------------------------------------------------------------
extern "C" void kernel_launch(void* const* d_in, const int* in_sizes, int n_in,
                              void* d_out, int out_size, void* d_ws,
                              size_t ws_size, hipStream_t stream) {
    const float* x   = (const float*)d_in[0];
    const int*   ei  = (const int*)d_in[1];
    const float* Wl1 = (const float*)d_in[2];
    const float* bl1 = (const float*)d_in[3];
    const float* Wr1 = (const float*)d_in[4];
    const float* Wl2 = (const float*)d_in[5];
    const float* bl2 = (const float*)d_in[6];
    const float* Wr2 = (const float*)d_in[7];
    float* out = (float*)d_out;

    float* ws   = (float*)d_ws;
    float* agg1 = ws;                            // N*64
    float* cnt  = agg1 + (size_t)N_NODES * 64;   // N
    float* agg2 = cnt + N_NODES;                 // N*40
    float* y1   = agg2 + (size_t)N_NODES * 40;   // N*64
    float* y2   = y1 + (size_t)N_NODES * 64;     // N*40
    float* z2   = y2 + (size_t)N_NODES * 40;     // N*40

    // zero agg1 | cnt | agg2 (contiguous)
    hipMemsetAsync(agg1, 0, (size_t)N_NODES * (64 + 1 + 40) * sizeof(float),
                   stream);

    k_gemm_y1<<<2048, 256, 0, stream>>>(x, Wl1, y1);
    k_agg1<<<(N_EDGES * 16) / 256, 256, 0, stream>>>(ei, y1, agg1, cnt);
    k_layer1_finish<<<2048, 256, 0, stream>>>(x, Wr1, bl1, Wl2, Wr2, agg1, cnt,
                                              y2, z2);
    k_agg2<<<(N_EDGES * 10 + 255) / 256, 256, 0, stream>>>(ei, y2, agg2);
    k_out<<<(N_NODES + 3) / 4, 256, 0, stream>>>(agg2, z2, cnt, bl2, out);
}

// Round 2
// 795.754 us; speedup vs baseline: 3.5048x; 3.5048x over previous
//
#include <hip/hip_runtime.h>

#define N_NODES 100000
#define N_EDGES 1600000
#define C_IN 128
#define C_H 64
#define C_OUT 40

// ---------------------------------------------------------------------------
// CSR build: deg -> exclusive scan -> slot-scatter
// ---------------------------------------------------------------------------
__global__ __launch_bounds__(256) void k_deg(const int* __restrict__ ei,
                                             int* __restrict__ deg) {
    int e = blockIdx.x * 256 + threadIdx.x;
    if (e < N_EDGES) atomicAdd(&deg[ei[N_EDGES + e]], 1);
}

__global__ __launch_bounds__(1024) void k_scan(const int* __restrict__ deg,
                                               int* __restrict__ row_ptr) {
    const int T = 1024;
    const int chunk = (N_NODES + T - 1) / T;  // 98
    int t = threadIdx.x;
    int b = t * chunk, e = min(b + chunk, N_NODES);
    int s = 0;
    for (int i = b; i < e; ++i) s += deg[i];
    __shared__ int ls[T];
    ls[t] = s;
    __syncthreads();
    for (int off = 1; off < T; off <<= 1) {
        int v = (t >= off) ? ls[t - off] : 0;
        __syncthreads();
        ls[t] += v;
        __syncthreads();
    }
    int run = (t == 0) ? 0 : ls[t - 1];
    for (int i = b; i < e; ++i) { row_ptr[i] = run; run += deg[i]; }
    if (e == N_NODES && b < e) row_ptr[N_NODES] = run;
}

__global__ __launch_bounds__(256) void k_fill(const int* __restrict__ ei,
                                              const int* __restrict__ row_ptr,
                                              int* __restrict__ ctr,
                                              int* __restrict__ csr) {
    int e = blockIdx.x * 256 + threadIdx.x;
    if (e < N_EDGES) {
        int dst = ei[N_EDGES + e];
        int pos = row_ptr[dst] + atomicAdd(&ctr[dst], 1);
        csr[pos] = ei[e];
    }
}

// ---------------------------------------------------------------------------
// K1: y1 = x @ Wl1^T   [N, 64]
// ---------------------------------------------------------------------------
__global__ __launch_bounds__(256) void k_gemm_y1(const float* __restrict__ x,
                                                 const float* __restrict__ Wl1,
                                                 float* __restrict__ y1) {
    __shared__ float Wt[C_IN * C_H];
    __shared__ float xs[4][C_IN];
    for (int i = threadIdx.x; i < C_IN * C_H; i += 256) {
        int k = i >> 6, c = i & 63;
        Wt[i] = Wl1[c * C_IN + k];
    }
    __syncthreads();
    const int wave = threadIdx.x >> 6, lane = threadIdx.x & 63;
    for (int r0 = blockIdx.x * 4; r0 < N_NODES; r0 += gridDim.x * 4) {
        for (int i = threadIdx.x; i < 4 * C_IN; i += 256) {
            int rr = r0 + (i >> 7);
            xs[i >> 7][i & 127] = (rr < N_NODES) ? x[(long)rr * C_IN + (i & 127)] : 0.f;
        }
        __syncthreads();
        int r = r0 + wave;
        if (r < N_NODES) {
            float acc = 0.f;
#pragma unroll 8
            for (int k = 0; k < C_IN; ++k)
                acc = fmaf(xs[wave][k], Wt[k * C_H + lane], acc);
            y1[(long)r * C_H + lane] = acc;
        }
        __syncthreads();
    }
}

// ---------------------------------------------------------------------------
// K2: mean1[r] = mean_{s in N(r)} y1[s]   (gather, no atomics)
// wave per node; 4 groups x 16 lanes x float4 -> 4 gathers in flight.
// ---------------------------------------------------------------------------
__global__ __launch_bounds__(256) void k_gather1(const int* __restrict__ row_ptr,
                                                 const int* __restrict__ csr,
                                                 const float* __restrict__ y1,
                                                 float* __restrict__ mean1) {
    int wave = threadIdx.x >> 6, lane = threadIdx.x & 63;
    int r = blockIdx.x * 4 + wave;
    if (r >= N_NODES) return;
    int b = row_ptr[r], e = row_ptr[r + 1];
    int g = lane >> 4, l = lane & 15;
    float4 acc = {0.f, 0.f, 0.f, 0.f};
    for (int i = b + g; i < e; i += 4) {
        int s = csr[i];
        const float4 v = *(const float4*)(y1 + ((long)s << 6) + (l << 2));
        acc.x += v.x; acc.y += v.y; acc.z += v.z; acc.w += v.w;
    }
    for (int m = 16; m < 64; m <<= 1) {
        acc.x += __shfl_xor(acc.x, m);
        acc.y += __shfl_xor(acc.y, m);
        acc.z += __shfl_xor(acc.z, m);
        acc.w += __shfl_xor(acc.w, m);
    }
    if (g == 0) {
        float inv = 1.f / fmaxf((float)(e - b), 1.f);
        acc.x *= inv; acc.y *= inv; acc.z *= inv; acc.w *= inv;
        *(float4*)(mean1 + ((long)r << 6) + (l << 2)) = acc;
    }
}

// ---------------------------------------------------------------------------
// K3: fused  z1 = x@Wr1^T ; h = relu(mean1 + bl1 + z1) ; y2 = h@Wl2^T ; z2 = h@Wr2^T
// ---------------------------------------------------------------------------
__global__ __launch_bounds__(256) void k_layer1_finish(
    const float* __restrict__ x, const float* __restrict__ Wr1,
    const float* __restrict__ bl1, const float* __restrict__ Wl2,
    const float* __restrict__ Wr2, const float* __restrict__ mean1,
    float* __restrict__ y2, float* __restrict__ z2) {
    __shared__ float Wr1t[C_IN * C_H];
    __shared__ float W2t[2][C_H * C_OUT];
    __shared__ float xs[4][C_IN];
    __shared__ float hs[4][C_H];
    for (int i = threadIdx.x; i < C_IN * C_H; i += 256) {
        int k = i >> 6, c = i & 63;
        Wr1t[i] = Wr1[c * C_IN + k];
    }
    for (int i = threadIdx.x; i < C_H * C_OUT; i += 256) {
        int k = i / C_OUT, cc = i - k * C_OUT;
        W2t[0][i] = Wl2[cc * C_H + k];
        W2t[1][i] = Wr2[cc * C_H + k];
    }
    __syncthreads();
    const int wave = threadIdx.x >> 6, lane = threadIdx.x & 63;
    for (int r0 = blockIdx.x * 4; r0 < N_NODES; r0 += gridDim.x * 4) {
        for (int i = threadIdx.x; i < 4 * C_IN; i += 256) {
            int rr = r0 + (i >> 7);
            xs[i >> 7][i & 127] = (rr < N_NODES) ? x[(long)rr * C_IN + (i & 127)] : 0.f;
        }
        __syncthreads();
        int r = r0 + wave;
        if (r < N_NODES) {
            float z = 0.f;
#pragma unroll 8
            for (int k = 0; k < C_IN; ++k)
                z = fmaf(xs[wave][k], Wr1t[k * C_H + lane], z);
            float h = mean1[(long)r * C_H + lane] + bl1[lane] + z;
            hs[wave][lane] = fmaxf(h, 0.f);
        }
        __syncthreads();
        if (r < N_NODES && lane < C_OUT) {
            float a = 0.f, bb = 0.f;
#pragma unroll 8
            for (int k = 0; k < C_H; ++k) {
                float hk = hs[wave][k];
                a = fmaf(hk, W2t[0][k * C_OUT + lane], a);
                bb = fmaf(hk, W2t[1][k * C_OUT + lane], bb);
            }
            y2[(long)r * C_OUT + lane] = a;
            z2[(long)r * C_OUT + lane] = bb;
        }
        __syncthreads();
    }
}

// ---------------------------------------------------------------------------
// K4: fused gather-mean of y2 + bias + z2 + softmax -> out. Wave per node.
// 4 groups x (10 active of 16) lanes x float4.
// ---------------------------------------------------------------------------
__global__ __launch_bounds__(256) void k_gather2_out(
    const int* __restrict__ row_ptr, const int* __restrict__ csr,
    const float* __restrict__ y2, const float* __restrict__ z2,
    const float* __restrict__ bl2, float* __restrict__ out) {
    int wave = threadIdx.x >> 6, lane = threadIdx.x & 63;
    int r = blockIdx.x * 4 + wave;
    if (r >= N_NODES) return;
    int b = row_ptr[r], e = row_ptr[r + 1];
    int g = lane >> 4, l = lane & 15;
    float4 acc = {0.f, 0.f, 0.f, 0.f};
    if (l < 10) {
        for (int i = b + g; i < e; i += 4) {
            int s = csr[i];
            const float4 v = *(const float4*)(y2 + (long)s * C_OUT + (l << 2));
            acc.x += v.x; acc.y += v.y; acc.z += v.z; acc.w += v.w;
        }
    }
    for (int m = 16; m < 64; m <<= 1) {
        acc.x += __shfl_xor(acc.x, m);
        acc.y += __shfl_xor(acc.y, m);
        acc.z += __shfl_xor(acc.z, m);
        acc.w += __shfl_xor(acc.w, m);
    }
    float4 o = {-1e30f, -1e30f, -1e30f, -1e30f};
    if (l < 10) {
        float inv = 1.f / fmaxf((float)(e - b), 1.f);
        const float4 zz = *(const float4*)(z2 + (long)r * C_OUT + (l << 2));
        const float4 bb = *(const float4*)(bl2 + (l << 2));
        o.x = acc.x * inv + bb.x + zz.x;
        o.y = acc.y * inv + bb.y + zz.y;
        o.z = acc.z * inv + bb.z + zz.z;
        o.w = acc.w * inv + bb.w + zz.w;
    }
    float mx = fmaxf(fmaxf(o.x, o.y), fmaxf(o.z, o.w));
    for (int m = 1; m < 16; m <<= 1) mx = fmaxf(mx, __shfl_xor(mx, m));
    float4 ex;
    ex.x = __expf(o.x - mx); ex.y = __expf(o.y - mx);
    ex.z = __expf(o.z - mx); ex.w = __expf(o.w - mx);
    float sm = ex.x + ex.y + ex.z + ex.w;
    for (int m = 1; m < 16; m <<= 1) sm += __shfl_xor(sm, m);
    if (g == 0 && l < 10) {
        float inv = 1.f / sm;
        float4 res = {ex.x * inv, ex.y * inv, ex.z * inv, ex.w * inv};
        *(float4*)(out + (long)r * C_OUT + (l << 2)) = res;
    }
}

// ---------------------------------------------------------------------------
extern "C" void kernel_launch(void* const* d_in, const int* in_sizes, int n_in,
                              void* d_out, int out_size, void* d_ws,
                              size_t ws_size, hipStream_t stream) {
    const float* x   = (const float*)d_in[0];
    const int*   ei  = (const int*)d_in[1];
    const float* Wl1 = (const float*)d_in[2];
    const float* bl1 = (const float*)d_in[3];
    const float* Wr1 = (const float*)d_in[4];
    const float* Wl2 = (const float*)d_in[5];
    const float* bl2 = (const float*)d_in[6];
    const float* Wr2 = (const float*)d_in[7];
    float* out = (float*)d_out;

    // workspace layout (16B-aligned float region: 1,900,004 ints * 4 = 7,600,016 B)
    int* deg     = (int*)d_ws;                 // N      (N % 4 == 0)
    int* ctr     = deg + N_NODES;              // N
    int* row_ptr = ctr + N_NODES;              // N+4 (padded for alignment)
    int* csr     = row_ptr + N_NODES + 4;      // E
    float* y1    = (float*)(csr + N_EDGES);    // N*64
    float* mean1 = y1 + (size_t)N_NODES * 64;  // N*64
    float* y2    = mean1 + (size_t)N_NODES * 64; // N*40
    float* z2    = y2 + (size_t)N_NODES * 40;  // N*40

    hipMemsetAsync(deg, 0, (size_t)2 * N_NODES * sizeof(int), stream);

    k_deg<<<(N_EDGES + 255) / 256, 256, 0, stream>>>(ei, deg);
    k_scan<<<1, 1024, 0, stream>>>(deg, row_ptr);
    k_fill<<<(N_EDGES + 255) / 256, 256, 0, stream>>>(ei, row_ptr, ctr, csr);

    k_gemm_y1<<<2048, 256, 0, stream>>>(x, Wl1, y1);
    k_gather1<<<(N_NODES + 3) / 4, 256, 0, stream>>>(row_ptr, csr, y1, mean1);
    k_layer1_finish<<<2048, 256, 0, stream>>>(x, Wr1, bl1, Wl2, Wr2, mean1, y2, z2);
    k_gather2_out<<<(N_NODES + 3) / 4, 256, 0, stream>>>(row_ptr, csr, y2, z2, bl2, out);
}

// Round 3
// 604.929 us; speedup vs baseline: 4.6104x; 1.3155x over previous
//
#include <hip/hip_runtime.h>

#define N_NODES 100000
#define N_EDGES 1600000
#define C_IN 128
#define C_H 64
#define C_OUT 40

#define XS_PAD 132   // x tile row stride (floats): 2-way max on b128 reads, 16B aligned
#define W1_PAD 68    // W1^T row stride: 2-way max
#define H_PAD 68
#define W2_PAD 84    // 80 cols + 4; 5*tj scalar reads conflict-free (gcd(5,32)=1)

// ---------------------------------------------------------------------------
// CSR build: deg -> exclusive scan -> slot-scatter
// ---------------------------------------------------------------------------
__global__ __launch_bounds__(256) void k_deg(const int* __restrict__ ei,
                                             int* __restrict__ deg) {
    int e = blockIdx.x * 256 + threadIdx.x;
    if (e < N_EDGES) atomicAdd(&deg[ei[N_EDGES + e]], 1);
}

__global__ __launch_bounds__(1024) void k_scan(const int* __restrict__ deg,
                                               int* __restrict__ row_ptr) {
    const int T = 1024;
    const int chunk = (N_NODES + T - 1) / T;
    int t = threadIdx.x;
    int b = t * chunk, e = min(b + chunk, N_NODES);
    int s = 0;
    for (int i = b; i < e; ++i) s += deg[i];
    __shared__ int ls[T];
    ls[t] = s;
    __syncthreads();
    for (int off = 1; off < T; off <<= 1) {
        int v = (t >= off) ? ls[t - off] : 0;
        __syncthreads();
        ls[t] += v;
        __syncthreads();
    }
    int run = (t == 0) ? 0 : ls[t - 1];
    for (int i = b; i < e; ++i) { row_ptr[i] = run; run += deg[i]; }
    if (e == N_NODES && b < e) row_ptr[N_NODES] = run;
}

__global__ __launch_bounds__(256) void k_fill(const int* __restrict__ ei,
                                              const int* __restrict__ row_ptr,
                                              int* __restrict__ ctr,
                                              int* __restrict__ csr) {
    int e = blockIdx.x * 256 + threadIdx.x;
    if (e < N_EDGES) {
        int dst = ei[N_EDGES + e];
        int pos = row_ptr[dst] + atomicAdd(&ctr[dst], 1);
        csr[pos] = ei[e];
    }
}

// ---------------------------------------------------------------------------
// K1: y1 = x @ Wl1^T.  64-row tile, 256 threads, 4x4 register block/thread.
// ---------------------------------------------------------------------------
__global__ __launch_bounds__(256) void k_gemm1(const float* __restrict__ x,
                                               const float* __restrict__ Wl1,
                                               float* __restrict__ y1) {
    __shared__ float Ws[C_IN * W1_PAD];   // Ws[k][c] = Wl1[c][k]
    __shared__ float xs[64 * XS_PAD];     // xs[row][k]
    const int tid = threadIdx.x;
    for (int i = tid; i < C_H * C_IN; i += 256) {
        int c = i >> 7, k = i & 127;
        Ws[k * W1_PAD + c] = Wl1[i];
    }
    const int r0 = blockIdx.x * 64;
#pragma unroll
    for (int it = 0; it < 8; ++it) {
        int idx = tid * 4 + it * 1024;
        int row = idx >> 7, k = idx & 127;
        int gr = min(r0 + row, N_NODES - 1);
        float4 v = *(const float4*)(x + (long)gr * C_IN + k);
        *(float4*)(xs + row * XS_PAD + k) = v;
    }
    __syncthreads();
    const int ti = tid >> 4, tj = tid & 15;
    float acc[4][4] = {};
    for (int k0 = 0; k0 < C_IN; k0 += 4) {
        float4 xr[4], wv[4];
#pragma unroll
        for (int rr = 0; rr < 4; ++rr)
            xr[rr] = *(const float4*)(xs + (ti * 4 + rr) * XS_PAD + k0);
#pragma unroll
        for (int kk = 0; kk < 4; ++kk)
            wv[kk] = *(const float4*)(Ws + (k0 + kk) * W1_PAD + tj * 4);
#pragma unroll
        for (int rr = 0; rr < 4; ++rr) {
            const float* xp = (const float*)&xr[rr];
#pragma unroll
            for (int kk = 0; kk < 4; ++kk) {
                float xv = xp[kk];
                const float* wp = (const float*)&wv[kk];
                acc[rr][0] = fmaf(xv, wp[0], acc[rr][0]);
                acc[rr][1] = fmaf(xv, wp[1], acc[rr][1]);
                acc[rr][2] = fmaf(xv, wp[2], acc[rr][2]);
                acc[rr][3] = fmaf(xv, wp[3], acc[rr][3]);
            }
        }
    }
#pragma unroll
    for (int rr = 0; rr < 4; ++rr) {
        int row = r0 + ti * 4 + rr;
        if (row < N_NODES)
            *(float4*)(y1 + (long)row * C_H + tj * 4) = *(const float4*)acc[rr];
    }
}

// ---------------------------------------------------------------------------
// K2: mean1[r] = mean_{s in N(r)} y1[s]   (gather, no atomics)
// ---------------------------------------------------------------------------
__global__ __launch_bounds__(256) void k_gather1(const int* __restrict__ row_ptr,
                                                 const int* __restrict__ csr,
                                                 const float* __restrict__ y1,
                                                 float* __restrict__ mean1) {
    int wave = threadIdx.x >> 6, lane = threadIdx.x & 63;
    int r = blockIdx.x * 4 + wave;
    if (r >= N_NODES) return;
    int b = row_ptr[r], e = row_ptr[r + 1];
    int g = lane >> 4, l = lane & 15;
    float4 acc = {0.f, 0.f, 0.f, 0.f};
    for (int i = b + g; i < e; i += 4) {
        int s = csr[i];
        const float4 v = *(const float4*)(y1 + ((long)s << 6) + (l << 2));
        acc.x += v.x; acc.y += v.y; acc.z += v.z; acc.w += v.w;
    }
    for (int m = 16; m < 64; m <<= 1) {
        acc.x += __shfl_xor(acc.x, m);
        acc.y += __shfl_xor(acc.y, m);
        acc.z += __shfl_xor(acc.z, m);
        acc.w += __shfl_xor(acc.w, m);
    }
    if (g == 0) {
        float inv = 1.f / fmaxf((float)(e - b), 1.f);
        acc.x *= inv; acc.y *= inv; acc.z *= inv; acc.w *= inv;
        *(float4*)(mean1 + ((long)r << 6) + (l << 2)) = acc;
    }
}

// ---------------------------------------------------------------------------
// K3: fused  z1 = x@Wr1^T (K=128) ; h = relu(mean1+bl1+z1) in LDS ;
//            [y2|z2] = h @ [Wl2^T|Wr2^T]  (K=64, 80 cols)
// ---------------------------------------------------------------------------
__global__ __launch_bounds__(256) void k_layer2(
    const float* __restrict__ x, const float* __restrict__ Wr1,
    const float* __restrict__ bl1, const float* __restrict__ Wl2,
    const float* __restrict__ Wr2, const float* __restrict__ mean1,
    float* __restrict__ y2, float* __restrict__ z2) {
    __shared__ float W1s[C_IN * W1_PAD];  // Wr1^T [k][c]
    __shared__ float xs[64 * XS_PAD];
    __shared__ float hs[64 * H_PAD];      // h tile [row][k2]
    __shared__ float W2s[C_H * W2_PAD];   // [k2][c], c<40: Wl2^T, 40..79: Wr2^T
    const int tid = threadIdx.x;
    for (int i = tid; i < C_H * C_IN; i += 256) {
        int c = i >> 7, k = i & 127;
        W1s[k * W1_PAD + c] = Wr1[i];
    }
    for (int i = tid; i < C_OUT * C_H; i += 256) {
        int c = i >> 6, k = i & 63;
        W2s[k * W2_PAD + c] = Wl2[i];
        W2s[k * W2_PAD + 40 + c] = Wr2[i];
    }
    const int r0 = blockIdx.x * 64;
#pragma unroll
    for (int it = 0; it < 8; ++it) {
        int idx = tid * 4 + it * 1024;
        int row = idx >> 7, k = idx & 127;
        int gr = min(r0 + row, N_NODES - 1);
        float4 v = *(const float4*)(x + (long)gr * C_IN + k);
        *(float4*)(xs + row * XS_PAD + k) = v;
    }
    __syncthreads();
    const int ti = tid >> 4, tj = tid & 15;
    // ---- phase 1: z tile (4 rows x 4 cols per thread over 64x64) ----
    {
        float acc[4][4] = {};
        for (int k0 = 0; k0 < C_IN; k0 += 4) {
            float4 xr[4], wv[4];
#pragma unroll
            for (int rr = 0; rr < 4; ++rr)
                xr[rr] = *(const float4*)(xs + (ti * 4 + rr) * XS_PAD + k0);
#pragma unroll
            for (int kk = 0; kk < 4; ++kk)
                wv[kk] = *(const float4*)(W1s + (k0 + kk) * W1_PAD + tj * 4);
#pragma unroll
            for (int rr = 0; rr < 4; ++rr) {
                const float* xp = (const float*)&xr[rr];
#pragma unroll
                for (int kk = 0; kk < 4; ++kk) {
                    float xv = xp[kk];
                    const float* wp = (const float*)&wv[kk];
                    acc[rr][0] = fmaf(xv, wp[0], acc[rr][0]);
                    acc[rr][1] = fmaf(xv, wp[1], acc[rr][1]);
                    acc[rr][2] = fmaf(xv, wp[2], acc[rr][2]);
                    acc[rr][3] = fmaf(xv, wp[3], acc[rr][3]);
                }
            }
        }
        const float4 bb = *(const float4*)(bl1 + tj * 4);
#pragma unroll
        for (int rr = 0; rr < 4; ++rr) {
            int gr = min(r0 + ti * 4 + rr, N_NODES - 1);
            const float4 m = *(const float4*)(mean1 + (long)gr * C_H + tj * 4);
            float4 h;
            h.x = fmaxf(acc[rr][0] + m.x + bb.x, 0.f);
            h.y = fmaxf(acc[rr][1] + m.y + bb.y, 0.f);
            h.z = fmaxf(acc[rr][2] + m.z + bb.z, 0.f);
            h.w = fmaxf(acc[rr][3] + m.w + bb.w, 0.f);
            *(float4*)(hs + (ti * 4 + rr) * H_PAD + tj * 4) = h;
        }
    }
    __syncthreads();
    // ---- phase 2: [y2|z2] tile (4 rows x 5 cols per thread over 64x80) ----
    {
        float acc[4][5] = {};
        for (int k0 = 0; k0 < C_H; k0 += 4) {
            float4 hr[4];
#pragma unroll
            for (int rr = 0; rr < 4; ++rr)
                hr[rr] = *(const float4*)(hs + (ti * 4 + rr) * H_PAD + k0);
            float wv[4][5];
#pragma unroll
            for (int kk = 0; kk < 4; ++kk)
#pragma unroll
                for (int cc = 0; cc < 5; ++cc)
                    wv[kk][cc] = W2s[(k0 + kk) * W2_PAD + tj * 5 + cc];
#pragma unroll
            for (int rr = 0; rr < 4; ++rr) {
                const float* hp = (const float*)&hr[rr];
#pragma unroll
                for (int kk = 0; kk < 4; ++kk) {
                    float hv = hp[kk];
#pragma unroll
                    for (int cc = 0; cc < 5; ++cc)
                        acc[rr][cc] = fmaf(hv, wv[kk][cc], acc[rr][cc]);
                }
            }
        }
#pragma unroll
        for (int rr = 0; rr < 4; ++rr) {
            int row = r0 + ti * 4 + rr;
            if (row < N_NODES) {
#pragma unroll
                for (int cc = 0; cc < 5; ++cc) {
                    int c = tj * 5 + cc;
                    if (c < C_OUT)
                        y2[(long)row * C_OUT + c] = acc[rr][cc];
                    else
                        z2[(long)row * C_OUT + (c - C_OUT)] = acc[rr][cc];
                }
            }
        }
    }
}

// ---------------------------------------------------------------------------
// K4: fused gather-mean of y2 + bias + z2 + softmax -> out. Wave per node.
// ---------------------------------------------------------------------------
__global__ __launch_bounds__(256) void k_gather2_out(
    const int* __restrict__ row_ptr, const int* __restrict__ csr,
    const float* __restrict__ y2, const float* __restrict__ z2,
    const float* __restrict__ bl2, float* __restrict__ out) {
    int wave = threadIdx.x >> 6, lane = threadIdx.x & 63;
    int r = blockIdx.x * 4 + wave;
    if (r >= N_NODES) return;
    int b = row_ptr[r], e = row_ptr[r + 1];
    int g = lane >> 4, l = lane & 15;
    float4 acc = {0.f, 0.f, 0.f, 0.f};
    if (l < 10) {
        for (int i = b + g; i < e; i += 4) {
            int s = csr[i];
            const float4 v = *(const float4*)(y2 + (long)s * C_OUT + (l << 2));
            acc.x += v.x; acc.y += v.y; acc.z += v.z; acc.w += v.w;
        }
    }
    for (int m = 16; m < 64; m <<= 1) {
        acc.x += __shfl_xor(acc.x, m);
        acc.y += __shfl_xor(acc.y, m);
        acc.z += __shfl_xor(acc.z, m);
        acc.w += __shfl_xor(acc.w, m);
    }
    float4 o = {-1e30f, -1e30f, -1e30f, -1e30f};
    if (l < 10) {
        float inv = 1.f / fmaxf((float)(e - b), 1.f);
        const float4 zz = *(const float4*)(z2 + (long)r * C_OUT + (l << 2));
        const float4 bb = *(const float4*)(bl2 + (l << 2));
        o.x = acc.x * inv + bb.x + zz.x;
        o.y = acc.y * inv + bb.y + zz.y;
        o.z = acc.z * inv + bb.z + zz.z;
        o.w = acc.w * inv + bb.w + zz.w;
    }
    float mx = fmaxf(fmaxf(o.x, o.y), fmaxf(o.z, o.w));
    for (int m = 1; m < 16; m <<= 1) mx = fmaxf(mx, __shfl_xor(mx, m));
    float4 ex;
    ex.x = __expf(o.x - mx); ex.y = __expf(o.y - mx);
    ex.z = __expf(o.z - mx); ex.w = __expf(o.w - mx);
    float sm = ex.x + ex.y + ex.z + ex.w;
    for (int m = 1; m < 16; m <<= 1) sm += __shfl_xor(sm, m);
    if (g == 0 && l < 10) {
        float inv = 1.f / sm;
        float4 res = {ex.x * inv, ex.y * inv, ex.z * inv, ex.w * inv};
        *(float4*)(out + (long)r * C_OUT + (l << 2)) = res;
    }
}

// ---------------------------------------------------------------------------
extern "C" void kernel_launch(void* const* d_in, const int* in_sizes, int n_in,
                              void* d_out, int out_size, void* d_ws,
                              size_t ws_size, hipStream_t stream) {
    const float* x   = (const float*)d_in[0];
    const int*   ei  = (const int*)d_in[1];
    const float* Wl1 = (const float*)d_in[2];
    const float* bl1 = (const float*)d_in[3];
    const float* Wr1 = (const float*)d_in[4];
    const float* Wl2 = (const float*)d_in[5];
    const float* bl2 = (const float*)d_in[6];
    const float* Wr2 = (const float*)d_in[7];
    float* out = (float*)d_out;

    int* deg     = (int*)d_ws;                 // N
    int* ctr     = deg + N_NODES;              // N
    int* row_ptr = ctr + N_NODES;              // N+4
    int* csr     = row_ptr + N_NODES + 4;      // E
    float* y1    = (float*)(csr + N_EDGES);    // N*64
    float* mean1 = y1 + (size_t)N_NODES * 64;  // N*64
    float* y2    = mean1 + (size_t)N_NODES * 64; // N*40
    float* z2    = y2 + (size_t)N_NODES * 40;  // N*40

    hipMemsetAsync(deg, 0, (size_t)2 * N_NODES * sizeof(int), stream);

    k_deg<<<(N_EDGES + 255) / 256, 256, 0, stream>>>(ei, deg);
    k_scan<<<1, 1024, 0, stream>>>(deg, row_ptr);
    k_fill<<<(N_EDGES + 255) / 256, 256, 0, stream>>>(ei, row_ptr, ctr, csr);

    const int ntiles = (N_NODES + 63) / 64;
    k_gemm1<<<ntiles, 256, 0, stream>>>(x, Wl1, y1);
    k_gather1<<<(N_NODES + 3) / 4, 256, 0, stream>>>(row_ptr, csr, y1, mean1);
    k_layer2<<<ntiles, 256, 0, stream>>>(x, Wr1, bl1, Wl2, Wr2, mean1, y2, z2);
    k_gather2_out<<<(N_NODES + 3) / 4, 256, 0, stream>>>(row_ptr, csr, y2, z2, bl2, out);
}

// Round 4
// 455.023 us; speedup vs baseline: 6.1293x; 1.3294x over previous
//
#include <hip/hip_runtime.h>

#define N_NODES 100000
#define N_EDGES 1600000
#define C_IN 128
#define C_H 64
#define C_OUT 40

#define NCHUNK ((N_NODES + 255) / 256)   // 391

#define XS_PAD 132
#define W1_PAD 68
#define H_PAD 68
#define W2_PAD 84

// ---------------------------------------------------------------------------
// CSR build: deg -> 3-phase multi-block exclusive scan -> slot-scatter
// ---------------------------------------------------------------------------
__global__ __launch_bounds__(256) void k_deg(const int* __restrict__ ei,
                                             int* __restrict__ deg) {
    int e = blockIdx.x * 256 + threadIdx.x;
    if (e < N_EDGES) atomicAdd(&deg[ei[N_EDGES + e]], 1);
}

__global__ __launch_bounds__(256) void k_scan_part(const int* __restrict__ deg,
                                                   int* __restrict__ cs) {
    int idx = blockIdx.x * 256 + threadIdx.x;
    int d = (idx < N_NODES) ? deg[idx] : 0;
    for (int m = 1; m < 64; m <<= 1) d += __shfl_xor(d, m);
    __shared__ int ws[4];
    if ((threadIdx.x & 63) == 0) ws[threadIdx.x >> 6] = d;
    __syncthreads();
    if (threadIdx.x == 0) cs[blockIdx.x] = ws[0] + ws[1] + ws[2] + ws[3];
}

__global__ __launch_bounds__(512) void k_scan_chunks(int* __restrict__ cs) {
    __shared__ int ls[512];
    int t = threadIdx.x;
    ls[t] = (t < NCHUNK) ? cs[t] : 0;
    __syncthreads();
    for (int off = 1; off < 512; off <<= 1) {
        int v = (t >= off) ? ls[t - off] : 0;
        __syncthreads();
        ls[t] += v;
        __syncthreads();
    }
    if (t < NCHUNK) cs[t] = (t == 0) ? 0 : ls[t - 1];
}

__global__ __launch_bounds__(256) void k_scan_final(const int* __restrict__ deg,
                                                    const int* __restrict__ cs,
                                                    int* __restrict__ row_ptr) {
    __shared__ int ls[256];
    int b = blockIdx.x, t = threadIdx.x;
    int idx = b * 256 + t;
    int d = (idx < N_NODES) ? deg[idx] : 0;
    ls[t] = d;
    __syncthreads();
    for (int off = 1; off < 256; off <<= 1) {
        int v = (t >= off) ? ls[t - off] : 0;
        __syncthreads();
        ls[t] += v;
        __syncthreads();
    }
    int excl = ls[t] - d + cs[b];
    if (idx < N_NODES) row_ptr[idx] = excl;
    if (idx == N_NODES - 1) row_ptr[N_NODES] = excl + d;
}

__global__ __launch_bounds__(256) void k_fill(const int* __restrict__ ei,
                                              const int* __restrict__ row_ptr,
                                              int* __restrict__ ctr,
                                              int* __restrict__ csr) {
    int e = blockIdx.x * 256 + threadIdx.x;
    if (e < N_EDGES) {
        int dst = ei[N_EDGES + e];
        int pos = row_ptr[dst] + atomicAdd(&ctr[dst], 1);
        csr[pos] = ei[e];
    }
}

// ---------------------------------------------------------------------------
// K1: y1 = x @ Wl1^T.  64-row tile, 256 threads, 4x4 register block/thread.
// ---------------------------------------------------------------------------
__global__ __launch_bounds__(256) void k_gemm1(const float* __restrict__ x,
                                               const float* __restrict__ Wl1,
                                               float* __restrict__ y1) {
    __shared__ float Ws[C_IN * W1_PAD];
    __shared__ float xs[64 * XS_PAD];
    const int tid = threadIdx.x;
    for (int i = tid; i < C_H * C_IN; i += 256) {
        int c = i >> 7, k = i & 127;
        Ws[k * W1_PAD + c] = Wl1[i];
    }
    const int r0 = blockIdx.x * 64;
#pragma unroll
    for (int it = 0; it < 8; ++it) {
        int idx = tid * 4 + it * 1024;
        int row = idx >> 7, k = idx & 127;
        int gr = min(r0 + row, N_NODES - 1);
        float4 v = *(const float4*)(x + (long)gr * C_IN + k);
        *(float4*)(xs + row * XS_PAD + k) = v;
    }
    __syncthreads();
    const int ti = tid >> 4, tj = tid & 15;
    float acc[4][4] = {};
    for (int k0 = 0; k0 < C_IN; k0 += 4) {
        float4 xr[4], wv[4];
#pragma unroll
        for (int rr = 0; rr < 4; ++rr)
            xr[rr] = *(const float4*)(xs + (ti * 4 + rr) * XS_PAD + k0);
#pragma unroll
        for (int kk = 0; kk < 4; ++kk)
            wv[kk] = *(const float4*)(Ws + (k0 + kk) * W1_PAD + tj * 4);
#pragma unroll
        for (int rr = 0; rr < 4; ++rr) {
            const float* xp = (const float*)&xr[rr];
#pragma unroll
            for (int kk = 0; kk < 4; ++kk) {
                float xv = xp[kk];
                const float* wp = (const float*)&wv[kk];
                acc[rr][0] = fmaf(xv, wp[0], acc[rr][0]);
                acc[rr][1] = fmaf(xv, wp[1], acc[rr][1]);
                acc[rr][2] = fmaf(xv, wp[2], acc[rr][2]);
                acc[rr][3] = fmaf(xv, wp[3], acc[rr][3]);
            }
        }
    }
#pragma unroll
    for (int rr = 0; rr < 4; ++rr) {
        int row = r0 + ti * 4 + rr;
        if (row < N_NODES)
            *(float4*)(y1 + (long)row * C_H + tj * 4) = *(const float4*)acc[rr];
    }
}

// ---------------------------------------------------------------------------
// K2: mean1[r] = mean_{s in N(r)} y1[s]   (gather, no atomics)
// ---------------------------------------------------------------------------
__global__ __launch_bounds__(256) void k_gather1(const int* __restrict__ row_ptr,
                                                 const int* __restrict__ csr,
                                                 const float* __restrict__ y1,
                                                 float* __restrict__ mean1) {
    int wave = threadIdx.x >> 6, lane = threadIdx.x & 63;
    int r = blockIdx.x * 4 + wave;
    if (r >= N_NODES) return;
    int b = row_ptr[r], e = row_ptr[r + 1];
    int g = lane >> 4, l = lane & 15;
    float4 acc = {0.f, 0.f, 0.f, 0.f};
    for (int i = b + g; i < e; i += 4) {
        int s = csr[i];
        const float4 v = *(const float4*)(y1 + ((long)s << 6) + (l << 2));
        acc.x += v.x; acc.y += v.y; acc.z += v.z; acc.w += v.w;
    }
    for (int m = 16; m < 64; m <<= 1) {
        acc.x += __shfl_xor(acc.x, m);
        acc.y += __shfl_xor(acc.y, m);
        acc.z += __shfl_xor(acc.z, m);
        acc.w += __shfl_xor(acc.w, m);
    }
    if (g == 0) {
        float inv = 1.f / fmaxf((float)(e - b), 1.f);
        acc.x *= inv; acc.y *= inv; acc.z *= inv; acc.w *= inv;
        *(float4*)(mean1 + ((long)r << 6) + (l << 2)) = acc;
    }
}

// ---------------------------------------------------------------------------
// K3: fused  z1 = x@Wr1^T (K=128) ; h = relu(mean1+bl1+z1) in LDS ;
//            [y2|z2] = h @ [Wl2^T|Wr2^T]  (K=64, 80 cols)
// ---------------------------------------------------------------------------
__global__ __launch_bounds__(256) void k_layer2(
    const float* __restrict__ x, const float* __restrict__ Wr1,
    const float* __restrict__ bl1, const float* __restrict__ Wl2,
    const float* __restrict__ Wr2, const float* __restrict__ mean1,
    float* __restrict__ y2, float* __restrict__ z2) {
    __shared__ float W1s[C_IN * W1_PAD];
    __shared__ float xs[64 * XS_PAD];
    __shared__ float hs[64 * H_PAD];
    __shared__ float W2s[C_H * W2_PAD];
    const int tid = threadIdx.x;
    for (int i = tid; i < C_H * C_IN; i += 256) {
        int c = i >> 7, k = i & 127;
        W1s[k * W1_PAD + c] = Wr1[i];
    }
    for (int i = tid; i < C_OUT * C_H; i += 256) {
        int c = i >> 6, k = i & 63;
        W2s[k * W2_PAD + c] = Wl2[i];
        W2s[k * W2_PAD + 40 + c] = Wr2[i];
    }
    const int r0 = blockIdx.x * 64;
#pragma unroll
    for (int it = 0; it < 8; ++it) {
        int idx = tid * 4 + it * 1024;
        int row = idx >> 7, k = idx & 127;
        int gr = min(r0 + row, N_NODES - 1);
        float4 v = *(const float4*)(x + (long)gr * C_IN + k);
        *(float4*)(xs + row * XS_PAD + k) = v;
    }
    __syncthreads();
    const int ti = tid >> 4, tj = tid & 15;
    {
        float acc[4][4] = {};
        for (int k0 = 0; k0 < C_IN; k0 += 4) {
            float4 xr[4], wv[4];
#pragma unroll
            for (int rr = 0; rr < 4; ++rr)
                xr[rr] = *(const float4*)(xs + (ti * 4 + rr) * XS_PAD + k0);
#pragma unroll
            for (int kk = 0; kk < 4; ++kk)
                wv[kk] = *(const float4*)(W1s + (k0 + kk) * W1_PAD + tj * 4);
#pragma unroll
            for (int rr = 0; rr < 4; ++rr) {
                const float* xp = (const float*)&xr[rr];
#pragma unroll
                for (int kk = 0; kk < 4; ++kk) {
                    float xv = xp[kk];
                    const float* wp = (const float*)&wv[kk];
                    acc[rr][0] = fmaf(xv, wp[0], acc[rr][0]);
                    acc[rr][1] = fmaf(xv, wp[1], acc[rr][1]);
                    acc[rr][2] = fmaf(xv, wp[2], acc[rr][2]);
                    acc[rr][3] = fmaf(xv, wp[3], acc[rr][3]);
                }
            }
        }
        const float4 bb = *(const float4*)(bl1 + tj * 4);
#pragma unroll
        for (int rr = 0; rr < 4; ++rr) {
            int gr = min(r0 + ti * 4 + rr, N_NODES - 1);
            const float4 m = *(const float4*)(mean1 + (long)gr * C_H + tj * 4);
            float4 h;
            h.x = fmaxf(acc[rr][0] + m.x + bb.x, 0.f);
            h.y = fmaxf(acc[rr][1] + m.y + bb.y, 0.f);
            h.z = fmaxf(acc[rr][2] + m.z + bb.z, 0.f);
            h.w = fmaxf(acc[rr][3] + m.w + bb.w, 0.f);
            *(float4*)(hs + (ti * 4 + rr) * H_PAD + tj * 4) = h;
        }
    }
    __syncthreads();
    {
        float acc[4][5] = {};
        for (int k0 = 0; k0 < C_H; k0 += 4) {
            float4 hr[4];
#pragma unroll
            for (int rr = 0; rr < 4; ++rr)
                hr[rr] = *(const float4*)(hs + (ti * 4 + rr) * H_PAD + k0);
            float wv[4][5];
#pragma unroll
            for (int kk = 0; kk < 4; ++kk)
#pragma unroll
                for (int cc = 0; cc < 5; ++cc)
                    wv[kk][cc] = W2s[(k0 + kk) * W2_PAD + tj * 5 + cc];
#pragma unroll
            for (int rr = 0; rr < 4; ++rr) {
                const float* hp = (const float*)&hr[rr];
#pragma unroll
                for (int kk = 0; kk < 4; ++kk) {
                    float hv = hp[kk];
#pragma unroll
                    for (int cc = 0; cc < 5; ++cc)
                        acc[rr][cc] = fmaf(hv, wv[kk][cc], acc[rr][cc]);
                }
            }
        }
#pragma unroll
        for (int rr = 0; rr < 4; ++rr) {
            int row = r0 + ti * 4 + rr;
            if (row < N_NODES) {
#pragma unroll
                for (int cc = 0; cc < 5; ++cc) {
                    int c = tj * 5 + cc;
                    if (c < C_OUT)
                        y2[(long)row * C_OUT + c] = acc[rr][cc];
                    else
                        z2[(long)row * C_OUT + (c - C_OUT)] = acc[rr][cc];
                }
            }
        }
    }
}

// ---------------------------------------------------------------------------
// K4: fused gather-mean of y2 + bias + z2 + softmax -> out. Wave per node.
// ---------------------------------------------------------------------------
__global__ __launch_bounds__(256) void k_gather2_out(
    const int* __restrict__ row_ptr, const int* __restrict__ csr,
    const float* __restrict__ y2, const float* __restrict__ z2,
    const float* __restrict__ bl2, float* __restrict__ out) {
    int wave = threadIdx.x >> 6, lane = threadIdx.x & 63;
    int r = blockIdx.x * 4 + wave;
    if (r >= N_NODES) return;
    int b = row_ptr[r], e = row_ptr[r + 1];
    int g = lane >> 4, l = lane & 15;
    float4 acc = {0.f, 0.f, 0.f, 0.f};
    if (l < 10) {
        for (int i = b + g; i < e; i += 4) {
            int s = csr[i];
            const float4 v = *(const float4*)(y2 + (long)s * C_OUT + (l << 2));
            acc.x += v.x; acc.y += v.y; acc.z += v.z; acc.w += v.w;
        }
    }
    for (int m = 16; m < 64; m <<= 1) {
        acc.x += __shfl_xor(acc.x, m);
        acc.y += __shfl_xor(acc.y, m);
        acc.z += __shfl_xor(acc.z, m);
        acc.w += __shfl_xor(acc.w, m);
    }
    float4 o = {-1e30f, -1e30f, -1e30f, -1e30f};
    if (l < 10) {
        float inv = 1.f / fmaxf((float)(e - b), 1.f);
        const float4 zz = *(const float4*)(z2 + (long)r * C_OUT + (l << 2));
        const float4 bb = *(const float4*)(bl2 + (l << 2));
        o.x = acc.x * inv + bb.x + zz.x;
        o.y = acc.y * inv + bb.y + zz.y;
        o.z = acc.z * inv + bb.z + zz.z;
        o.w = acc.w * inv + bb.w + zz.w;
    }
    float mx = fmaxf(fmaxf(o.x, o.y), fmaxf(o.z, o.w));
    for (int m = 1; m < 16; m <<= 1) mx = fmaxf(mx, __shfl_xor(mx, m));
    float4 ex;
    ex.x = __expf(o.x - mx); ex.y = __expf(o.y - mx);
    ex.z = __expf(o.z - mx); ex.w = __expf(o.w - mx);
    float sm = ex.x + ex.y + ex.z + ex.w;
    for (int m = 1; m < 16; m <<= 1) sm += __shfl_xor(sm, m);
    if (g == 0 && l < 10) {
        float inv = 1.f / sm;
        float4 res = {ex.x * inv, ex.y * inv, ex.z * inv, ex.w * inv};
        *(float4*)(out + (long)r * C_OUT + (l << 2)) = res;
    }
}

// ---------------------------------------------------------------------------
extern "C" void kernel_launch(void* const* d_in, const int* in_sizes, int n_in,
                              void* d_out, int out_size, void* d_ws,
                              size_t ws_size, hipStream_t stream) {
    const float* x   = (const float*)d_in[0];
    const int*   ei  = (const int*)d_in[1];
    const float* Wl1 = (const float*)d_in[2];
    const float* bl1 = (const float*)d_in[3];
    const float* Wr1 = (const float*)d_in[4];
    const float* Wl2 = (const float*)d_in[5];
    const float* bl2 = (const float*)d_in[6];
    const float* Wr2 = (const float*)d_in[7];
    float* out = (float*)d_out;

    int* deg     = (int*)d_ws;                 // N
    int* ctr     = deg + N_NODES;              // N
    int* cs      = ctr + N_NODES;              // 512 (chunk sums)
    int* row_ptr = cs + 512;                   // N+4
    int* csr     = row_ptr + N_NODES + 4;      // E
    float* y1    = (float*)(csr + N_EDGES);    // N*64
    float* mean1 = y1 + (size_t)N_NODES * 64;  // N*64
    float* y2    = mean1 + (size_t)N_NODES * 64; // N*40
    float* z2    = y2 + (size_t)N_NODES * 40;  // N*40

    hipMemsetAsync(deg, 0, (size_t)2 * N_NODES * sizeof(int), stream);

    k_deg<<<(N_EDGES + 255) / 256, 256, 0, stream>>>(ei, deg);
    k_scan_part<<<NCHUNK, 256, 0, stream>>>(deg, cs);
    k_scan_chunks<<<1, 512, 0, stream>>>(cs);
    k_scan_final<<<NCHUNK, 256, 0, stream>>>(deg, cs, row_ptr);
    k_fill<<<(N_EDGES + 255) / 256, 256, 0, stream>>>(ei, row_ptr, ctr, csr);

    const int ntiles = (N_NODES + 63) / 64;
    k_gemm1<<<ntiles, 256, 0, stream>>>(x, Wl1, y1);
    k_gather1<<<(N_NODES + 3) / 4, 256, 0, stream>>>(row_ptr, csr, y1, mean1);
    k_layer2<<<ntiles, 256, 0, stream>>>(x, Wr1, bl1, Wl2, Wr2, mean1, y2, z2);
    k_gather2_out<<<(N_NODES + 3) / 4, 256, 0, stream>>>(row_ptr, csr, y2, z2, bl2, out);
}